// Round 22
// baseline (589.356 us; speedup 1.0000x reference)
//
#include <hip/hip_runtime.h>

#define TT 2000
#define BB 64
#define HH 256
#define BH (BB*HH)
#define CH 4            // scan chunk = 4 time steps (ring 8KB)
#define NCH (TT/CH)     // 500 chunks
#define CROWS 64        // w_recP rows cached in LDS (s in [0,64))
#define NXT 1000        // GEMM x-tiles (each covers 2 t-values x all b)
#define SCANB 64        // scan blocks (one per batch)

#define BM 128
#define BN 128
#define BK 32
#define NKS (HH/BK)     // 8 K-steps

__device__ __forceinline__ float clip01(float x) { return fminf(fmaxf(x, 0.0f), 1.0f); }

// ---------------- weight prep ----------------
// w_inT[k][h]     = w_in[h][k]       (GEMM)
// w_recP[s][4l+j] = w_rec[l+64j][s]  (packed gather rows; value-verified)
__global__ void transpose2(const float* __restrict__ w_in, const float* __restrict__ w_rec,
                           float* __restrict__ w_inT, float* __restrict__ w_recP) {
    int idx = blockIdx.x * 256 + threadIdx.x;   // 65536 per matrix
    int h = idx >> 8, s = idx & 255;            // coalesced read over s
    w_inT[s * HH + h] = w_in[idx];
    int l = h & 63, j = h >> 6;
    w_recP[s * HH + 4 * l + j] = w_rec[idx];
}

// ---------------- fused kernel: GEMM blocks + scan blocks, flag-synced ----------------
// ALL blocks 256 threads (4 waves). LDS union 72KB -> 2 blocks/CU by LDS;
// 8 waves/CU = 2 waves/EU -> compiler VGPR budget 256 -> NO accumulator squeeze
// (the R19-R21 spiral: 8-wave blocks at 2 blocks/CU forced VGPR<=128 and the
// heuristic squeezed to 64-68, spilling the 64-float acc).
// blocks [0,64): scan (threads 0..127 active). wc holds rows 0..63;
//   m1,m2,m3 gathers from L2 (same values, ascending order -> bitwise same).
// blocks [64, 64+2000): GEMM 128x128 tile (R9 geometry) + 1-deep reg prefetch.
//   Tile x covers n'=t*64+b in [128x,128x+128) = t in {2x,2x+1}.
//   flags[x]==2 when both y-halves stored (release). GEMM blocks never wait.

__global__ __launch_bounds__(256) void fused(const float* __restrict__ X,
                                             const float* __restrict__ tau_syn,
                                             const float* __restrict__ tau_mem,
                                             const float* __restrict__ w_inT,
                                             const float* __restrict__ w_recP,
                                             int* flags,
                                             float* outp) {
    __shared__ __align__(16) char ldsraw[73728];   // scan{ring8K+wc64K} / gemm{XsT16.9K+Ws16.9K}
    int gx = blockIdx.x;

    if (gx >= SCANB) {
        // ================= GEMM block (R9 math/geometry + pipelined staging) ========
        float* XsT = (float*)ldsraw;                     // [BK][BM+4] = 4224 floats
        float* Ws  = XsT + BK * (BM + 4);                // [BK][BN+4] = 4224 floats
        int gg = gx - SCANB;
        int xt = gg >> 1, yy = gg & 1;
        int n0 = xt * BM, h0 = yy * BN;
        int tid = threadIdx.x;
        int ty = tid >> 4, tx = tid & 15;                // 16x16 thread grid, 8x8 each
        float acc[8][8] = {};

        // staging geometry (R9): X 128 rows x 32 k, W 32 k x 128 cols
        int r = tid & 127, kseg = (tid >> 7) * 16;       // X: row n0+r, 16 k's
        int np = n0 + r;
        const float* xsrc = X + ((size_t)(np & 63) * TT + (np >> 6)) * HH + kseg;
        int krow = tid >> 3, cs = (tid & 7) * 16;        // W: row kc+krow, 16 cols
        const float* wsrc = w_inT + (size_t)krow * HH + h0 + cs;

        float4 xr0, xr1, xr2, xr3, wr0, wr1, wr2, wr3;
        // prologue: issue K-step 0 loads
        xr0 = *(const float4*)(xsrc + 0);
        xr1 = *(const float4*)(xsrc + 4);
        xr2 = *(const float4*)(xsrc + 8);
        xr3 = *(const float4*)(xsrc + 12);
        wr0 = *(const float4*)(wsrc + 0);
        wr1 = *(const float4*)(wsrc + 4);
        wr2 = *(const float4*)(wsrc + 8);
        wr3 = *(const float4*)(wsrc + 12);

        for (int step = 0; step < NKS; ++step) {
            // write staged regs -> LDS
            XsT[(kseg + 0) * (BM + 4) + r]  = xr0.x;
            XsT[(kseg + 1) * (BM + 4) + r]  = xr0.y;
            XsT[(kseg + 2) * (BM + 4) + r]  = xr0.z;
            XsT[(kseg + 3) * (BM + 4) + r]  = xr0.w;
            XsT[(kseg + 4) * (BM + 4) + r]  = xr1.x;
            XsT[(kseg + 5) * (BM + 4) + r]  = xr1.y;
            XsT[(kseg + 6) * (BM + 4) + r]  = xr1.z;
            XsT[(kseg + 7) * (BM + 4) + r]  = xr1.w;
            XsT[(kseg + 8) * (BM + 4) + r]  = xr2.x;
            XsT[(kseg + 9) * (BM + 4) + r]  = xr2.y;
            XsT[(kseg + 10) * (BM + 4) + r] = xr2.z;
            XsT[(kseg + 11) * (BM + 4) + r] = xr2.w;
            XsT[(kseg + 12) * (BM + 4) + r] = xr3.x;
            XsT[(kseg + 13) * (BM + 4) + r] = xr3.y;
            XsT[(kseg + 14) * (BM + 4) + r] = xr3.z;
            XsT[(kseg + 15) * (BM + 4) + r] = xr3.w;
            *(float4*)&Ws[krow * (BN + 4) + cs]      = wr0;
            *(float4*)&Ws[krow * (BN + 4) + cs + 4]  = wr1;
            *(float4*)&Ws[krow * (BN + 4) + cs + 8]  = wr2;
            *(float4*)&Ws[krow * (BN + 4) + cs + 12] = wr3;
            __syncthreads();
            // issue NEXT K-step loads (in flight during compute below)
            if (step + 1 < NKS) {
                const float* xs = xsrc + (step + 1) * BK;
                const float* ws = wsrc + (size_t)(step + 1) * BK * HH;
                xr0 = *(const float4*)(xs + 0);
                xr1 = *(const float4*)(xs + 4);
                xr2 = *(const float4*)(xs + 8);
                xr3 = *(const float4*)(xs + 12);
                wr0 = *(const float4*)(ws + 0);
                wr1 = *(const float4*)(ws + 4);
                wr2 = *(const float4*)(ws + 8);
                wr3 = *(const float4*)(ws + 12);
            }
            // compute this K-step (kk ascending; same FMA order as R9)
#pragma unroll 4
            for (int kk = 0; kk < BK; kk++) {
                float4 a0 = *(const float4*)&XsT[kk * (BM + 4) + ty * 8];
                float4 a1 = *(const float4*)&XsT[kk * (BM + 4) + ty * 8 + 4];
                float4 b0 = *(const float4*)&Ws[kk * (BN + 4) + tx * 8];
                float4 b1 = *(const float4*)&Ws[kk * (BN + 4) + tx * 8 + 4];
                float a[8] = {a0.x, a0.y, a0.z, a0.w, a1.x, a1.y, a1.z, a1.w};
                float bb[8] = {b0.x, b0.y, b0.z, b0.w, b1.x, b1.y, b1.z, b1.w};
#pragma unroll
                for (int rr = 0; rr < 8; rr++)
#pragma unroll
                    for (int cc = 0; cc < 8; cc++)
                        acc[rr][cc] += a[rr] * bb[cc];
            }
            __syncthreads();   // all waves done reading before next overwrite
        }
#pragma unroll
        for (int rr = 0; rr < 8; rr++) {
            int npo = n0 + ty * 8 + rr;               // n' IS the out row (t*BB+b)
            float* dst = outp + (size_t)npo * HH + h0 + tx * 8;
            float4 s0 = {acc[rr][0], acc[rr][1], acc[rr][2], acc[rr][3]};
            float4 s1 = {acc[rr][4], acc[rr][5], acc[rr][6], acc[rr][7]};
            *(float4*)dst = s0;
            *(float4*)(dst + 4) = s1;
        }
        __syncthreads();   // all waves' stores drained (vmcnt(0) before barrier)
        if (tid == 0)
            __hip_atomic_fetch_add(&flags[xt], 1, __ATOMIC_RELEASE, __HIP_MEMORY_SCOPE_AGENT);
        return;
    }

    // ================= scan block (R20-verbatim) =================
    if (threadIdx.x >= 128) return;   // waves 2,3 unused (exit before any barrier)
    const float DT = 0.001f;
    float* ring = (float*)ldsraw;                  // 2*CH*HH floats = 8 KB
    float* wc   = ring + 2 * CH * HH;              // CROWS*HH floats = 64 KB
    int b = gx;
    int lane = threadIdx.x & 63;
    int wid = threadIdx.x >> 6;

    // cooperative wcache fill: w_recP rows 0..63 (128 threads, 32 iters)
    {
        const float4* src = (const float4*)w_recP;
        float4* dst = (float4*)wc;
#pragma unroll
        for (int q = 0; q < (CROWS * HH / 4) / 128; ++q)
            dst[q * 128 + threadIdx.x] = src[q * 128 + threadIdx.x];
    }

    if (wid == 1) {
        // ---- producer: flag-wait then stage xw chunks into LDS ring ----
        // chunk c needs t in [4c,4c+4) -> x-tiles 2c, 2c+1 (each ==2 when done)
#define WAITC(CC) do { int x0 = 2 * (CC);                                            \
            _Pragma("unroll")                                                        \
            for (int k = 0; k < 2; ++k)                                              \
                while (__hip_atomic_load(&flags[x0 + k], __ATOMIC_RELAXED,           \
                                         __HIP_MEMORY_SCOPE_AGENT) != 2)             \
                    __builtin_amdgcn_s_sleep(1);                                     \
            (void)__hip_atomic_load(&flags[x0], __ATOMIC_ACQUIRE,                    \
                                    __HIP_MEMORY_SCOPE_AGENT);                       \
        } while (0)
        WAITC(0);
        float4 rb[CH];
#pragma unroll
        for (int r2 = 0; r2 < CH; ++r2)
            rb[r2] = *(const float4*)(outp + ((size_t)r2 * BB + b) * HH + 4 * lane);
#pragma unroll
        for (int r2 = 0; r2 < CH; ++r2)
            *(float4*)&ring[r2 * HH + 4 * lane] = rb[r2];
        __syncthreads();
        for (int c = 0; c < NCH; ++c) {
            if (c + 1 < NCH) {
                WAITC(c + 1);
                int t0 = (c + 1) * CH;
                int lb = ((c + 1) & 1) * (CH * HH);
                float4 sb[CH];
#pragma unroll
                for (int r2 = 0; r2 < CH; ++r2)
                    sb[r2] = *(const float4*)(outp + ((size_t)(t0 + r2) * BB + b) * HH + 4 * lane);
#pragma unroll
                for (int r2 = 0; r2 < CH; ++r2)
                    *(float4*)&ring[lb + r2 * HH + 4 * lane] = sb[r2];
            }
            __syncthreads();
        }
        return;
    }

    // ---- consumer wave: R9 dynamics + immediate while-loop gather,
    //      packed float4 per spike, ascending m0,m1,m2,m3 sum order.
    //      m0 from LDS wc; m1,m2,m3 from L2 (same values -> bitwise same) ----
    int off = b * HH + lane;
    float am[4], bs[4];
#pragma unroll
    for (int j = 0; j < 4; j++) {
        am[j] = DT * clip01(tau_mem[lane + 64 * j]);
        bs[j] = DT * clip01(tau_syn[lane + 64 * j]);
    }

    float vv[4] = {0.f, 0.f, 0.f, 0.f};
    float ii[4] = {0.f, 0.f, 0.f, 0.f};
    float racc[4] = {0.f, 0.f, 0.f, 0.f};
    float zl[4] = {0.f, 0.f, 0.f, 0.f};
    float cur[4], nxt[4];
    unsigned stoff = (unsigned)off;

#define STEP()                                                                      \
    do {                                                                            \
        bool z[4];                                                                  \
        _Pragma("unroll")                                                           \
        for (int j = 0; j < 4; j++) {                                               \
            float vd = vv[j] + am[j] * (ii[j] - vv[j]);     /* v + DT*tmi*(-v+i) */ \
            float id = ii[j] - bs[j] * ii[j];               /* i - DT*tsi*i    */   \
            z[j] = (vd - 1.0f) > 0.0f;                                              \
            float zf = z[j] ? 1.0f : 0.0f;                                          \
            vv[j] = z[j] ? 0.0f : vd;                                               \
            ii[j] = (id + cur[j]) + racc[j];                /* (i_dec+xw)+rec */    \
            __builtin_nontemporal_store(zf, &outp[stoff + j * 64]);                 \
            zl[j] = zf;                                                             \
        }                                                                           \
        stoff += BH;                                                                \
        unsigned long long m0 = __ballot(z[0]);                                     \
        unsigned long long m1 = __ballot(z[1]);                                     \
        unsigned long long m2 = __ballot(z[2]);                                     \
        unsigned long long m3 = __ballot(z[3]);                                     \
        racc[0] = 0.0f; racc[1] = 0.0f; racc[2] = 0.0f; racc[3] = 0.0f;             \
        if ((m0 | m1 | m2 | m3) != 0ull) {                                          \
            unsigned long long m;                                                   \
            m = m0; while (m) { int bit = __builtin_ctzll(m); m &= m - 1;           \
                float4 e = *(const float4*)(wc + (bit << 8) + 4 * lane);            \
                racc[0] += e.x; racc[1] += e.y; racc[2] += e.z; racc[3] += e.w; }   \
            m = m1; while (m) { int bit = __builtin_ctzll(m); m &= m - 1;           \
                float4 e = *(const float4*)(w_recP + ((size_t)(64 + bit) << 8) + 4 * lane); \
                racc[0] += e.x; racc[1] += e.y; racc[2] += e.z; racc[3] += e.w; }   \
            m = m2; while (m) { int bit = __builtin_ctzll(m); m &= m - 1;           \
                float4 e = *(const float4*)(w_recP + ((size_t)(128 + bit) << 8) + 4 * lane); \
                racc[0] += e.x; racc[1] += e.y; racc[2] += e.z; racc[3] += e.w; }   \
            m = m3; while (m) { int bit = __builtin_ctzll(m); m &= m - 1;           \
                float4 e = *(const float4*)(w_recP + ((size_t)(192 + bit) << 8) + 4 * lane); \
                racc[0] += e.x; racc[1] += e.y; racc[2] += e.z; racc[3] += e.w; }   \
        }                                                                           \
    } while (0)

    __syncthreads();   // wcache + chunk 0 staged

    for (int c = 0; c < NCH; ++c) {
        int lb = (c & 1) * (CH * HH);
#pragma unroll
        for (int j = 0; j < 4; j++)
            cur[j] = ring[lb + lane + 64 * j];
        for (int u = 0; u < CH - 1; ++u) {
#pragma unroll
            for (int j = 0; j < 4; j++)
                nxt[j] = ring[lb + (u + 1) * HH + lane + 64 * j];
            STEP();
#pragma unroll
            for (int j = 0; j < 4; j++)
                cur[j] = nxt[j];
        }
        STEP();        // u = CH-1
        __syncthreads();
    }

    // final state: z_f, v_f, i_f (from registers)
#pragma unroll
    for (int j = 0; j < 4; j++) {
        outp[(size_t)TT * BH + b * HH + lane + 64 * j] = zl[j];
        outp[(size_t)TT * BH + BH + b * HH + lane + 64 * j] = vv[j];
        outp[(size_t)TT * BH + 2 * BH + b * HH + lane + 64 * j] = ii[j];
    }
}

extern "C" void kernel_launch(void* const* d_in, const int* in_sizes, int n_in,
                              void* d_out, int out_size, void* d_ws, size_t ws_size,
                              hipStream_t stream) {
    const float* x       = (const float*)d_in[0];
    const float* w_in    = (const float*)d_in[1];
    const float* w_rec   = (const float*)d_in[2];
    const float* tau_syn = (const float*)d_in[3];
    const float* tau_mem = (const float*)d_in[4];
    float* out = (float*)d_out;

    float* w_inT  = (float*)d_ws;              // 65536 floats
    float* w_recP = w_inT + HH * HH;           // 65536 floats
    int*   flags  = (int*)(w_recP + HH * HH);  // NXT ints

    hipMemsetAsync(flags, 0, NXT * sizeof(int), stream);
    transpose2<<<256, 256, 0, stream>>>(w_in, w_rec, w_inT, w_recP);
    fused<<<SCANB + 2 * NXT, 256, 0, stream>>>(x, tau_syn, tau_mem, w_inT, w_recP,
                                               flags, out);
}

// Round 23
// 403.277 us; speedup vs baseline: 1.4614x; 1.4614x over previous
//
#include <hip/hip_runtime.h>

#define TT 2000
#define BB 64
#define HH 256
#define BH (BB*HH)
#define CH 8            // scan chunk = 8 time steps
#define NCH (TT/CH)     // 250 chunks
#define CROWS 128       // w_recP rows cached in LDS (s in [0,128))
#define NXT 500         // GEMM x-tiles (each covers 4 t-values x all b)
#define SCANB 64        // scan blocks (one per batch)

#define BM 256
#define BN 128
#define BK 32
#define NKS (HH/BK)     // 8 K-steps

__device__ __forceinline__ float clip01(float x) { return fminf(fmaxf(x, 0.0f), 1.0f); }

// ---------------- weight prep ----------------
// w_inT[k][h]     = w_in[h][k]       (GEMM)
// w_recP[s][4l+j] = w_rec[l+64j][s]  (packed gather rows; value-verified)
__global__ void transpose2(const float* __restrict__ w_in, const float* __restrict__ w_rec,
                           float* __restrict__ w_inT, float* __restrict__ w_recP) {
    int idx = blockIdx.x * 256 + threadIdx.x;   // 65536 per matrix
    int h = idx >> 8, s = idx & 255;            // coalesced read over s
    w_inT[s * HH + h] = w_in[idx];
    int l = h & 63, j = h >> 6;
    w_recP[s * HH + 4 * l + j] = w_rec[idx];
}

// ---------------- fused kernel: GEMM blocks + scan blocks, flag-synced ----------------
// R15 champion configuration (401 us, absmax 0.0). 147KB union -> 1 block/CU,
// VGPR 128 spill-free (any higher occupancy target triggers the allocator's
// VGPR squeeze and spills the 64-float accumulator — R19-R22).
// blocks [0,64): scan (threads 0..127; rest exit).
// blocks [64,1064): GEMM 256x128 tile, 512 threads, software-pipelined staging
//   (next K-step's global loads in registers during compute).
//   Tile x covers n'=t*64+b in [256x,256x+256) = t in {4x..4x+3}.
//   flags[x]==2 when both h-halves stored (release). GEMM blocks never wait.

__global__ __launch_bounds__(512) void fused(const float* __restrict__ X,
                                             const float* __restrict__ tau_syn,
                                             const float* __restrict__ tau_mem,
                                             const float* __restrict__ w_inT,
                                             const float* __restrict__ w_recP,
                                             int* flags,
                                             float* outp) {
    __shared__ __align__(16) char ldsraw[147456];   // union: scan{ring16K+wc128K} / gemm{XsT+Ws 50K}
    int gx = blockIdx.x;

    if (gx >= SCANB) {
        // ================= GEMM block (R9 math, pipelined staging) =================
        float* XsT = (float*)ldsraw;                 // [BK][BM+4]  33.3KB
        float* Ws  = XsT + BK * (BM + 4);            // [BK][BN+4]  16.9KB
        int gg = gx - SCANB;
        int xt = gg >> 1, yy = gg & 1;
        int n0 = xt * BM, h0 = yy * BN;
        int tid = threadIdx.x;
        int ty = tid >> 4, tx = tid & 15;            // ty 0..31, tx 0..15
        float acc[8][8] = {};

        // staging geometry
        int r = tid & 255, kseg = (tid >> 8) * 16;   // X: row n0+r, 16 k's
        int np = n0 + r;
        const float* xsrc = X + ((size_t)(np & 63) * TT + (np >> 6)) * HH + kseg;
        int krow = tid >> 4, cs = (tid & 15) * 8;    // W: row kc+krow, 8 cols
        const float* wsrc = w_inT + (size_t)krow * HH + h0 + cs;

        float4 xr0, xr1, xr2, xr3, wr0, wr1;
        // prologue: issue K-step 0 loads
        xr0 = *(const float4*)(xsrc + 0);
        xr1 = *(const float4*)(xsrc + 4);
        xr2 = *(const float4*)(xsrc + 8);
        xr3 = *(const float4*)(xsrc + 12);
        wr0 = *(const float4*)(wsrc + 0);
        wr1 = *(const float4*)(wsrc + 4);

        for (int step = 0; step < NKS; ++step) {
            // write staged regs -> LDS (vmcnt wait inserted here by compiler)
            XsT[(kseg + 0) * (BM + 4) + r]  = xr0.x;
            XsT[(kseg + 1) * (BM + 4) + r]  = xr0.y;
            XsT[(kseg + 2) * (BM + 4) + r]  = xr0.z;
            XsT[(kseg + 3) * (BM + 4) + r]  = xr0.w;
            XsT[(kseg + 4) * (BM + 4) + r]  = xr1.x;
            XsT[(kseg + 5) * (BM + 4) + r]  = xr1.y;
            XsT[(kseg + 6) * (BM + 4) + r]  = xr1.z;
            XsT[(kseg + 7) * (BM + 4) + r]  = xr1.w;
            XsT[(kseg + 8) * (BM + 4) + r]  = xr2.x;
            XsT[(kseg + 9) * (BM + 4) + r]  = xr2.y;
            XsT[(kseg + 10) * (BM + 4) + r] = xr2.z;
            XsT[(kseg + 11) * (BM + 4) + r] = xr2.w;
            XsT[(kseg + 12) * (BM + 4) + r] = xr3.x;
            XsT[(kseg + 13) * (BM + 4) + r] = xr3.y;
            XsT[(kseg + 14) * (BM + 4) + r] = xr3.z;
            XsT[(kseg + 15) * (BM + 4) + r] = xr3.w;
            *(float4*)&Ws[krow * (BN + 4) + cs]     = wr0;
            *(float4*)&Ws[krow * (BN + 4) + cs + 4] = wr1;
            __syncthreads();
            // issue NEXT K-step loads (in flight during compute below)
            if (step + 1 < NKS) {
                const float* xs = xsrc + (step + 1) * BK;
                const float* ws = wsrc + (size_t)(step + 1) * BK * HH;
                xr0 = *(const float4*)(xs + 0);
                xr1 = *(const float4*)(xs + 4);
                xr2 = *(const float4*)(xs + 8);
                xr3 = *(const float4*)(xs + 12);
                wr0 = *(const float4*)(ws + 0);
                wr1 = *(const float4*)(ws + 4);
            }
            // compute this K-step (kk ascending; same FMA order as R9)
#pragma unroll 4
            for (int kk = 0; kk < BK; kk++) {
                float4 a0 = *(const float4*)&XsT[kk * (BM + 4) + ty * 8];
                float4 a1 = *(const float4*)&XsT[kk * (BM + 4) + ty * 8 + 4];
                float4 b0 = *(const float4*)&Ws[kk * (BN + 4) + tx * 8];
                float4 b1 = *(const float4*)&Ws[kk * (BN + 4) + tx * 8 + 4];
                float a[8] = {a0.x, a0.y, a0.z, a0.w, a1.x, a1.y, a1.z, a1.w};
                float bb[8] = {b0.x, b0.y, b0.z, b0.w, b1.x, b1.y, b1.z, b1.w};
#pragma unroll
                for (int rr = 0; rr < 8; rr++)
#pragma unroll
                    for (int cc = 0; cc < 8; cc++)
                        acc[rr][cc] += a[rr] * bb[cc];
            }
            __syncthreads();
        }
#pragma unroll
        for (int rr = 0; rr < 8; rr++) {
            int npo = n0 + ty * 8 + rr;               // n' IS the out row (t*BB+b)
            float* dst = outp + (size_t)npo * HH + h0 + tx * 8;
            float4 s0 = {acc[rr][0], acc[rr][1], acc[rr][2], acc[rr][3]};
            float4 s1 = {acc[rr][4], acc[rr][5], acc[rr][6], acc[rr][7]};
            *(float4*)dst = s0;
            *(float4*)(dst + 4) = s1;
        }
        __syncthreads();   // all waves' stores drained (vmcnt(0) before barrier)
        if (tid == 0)
            __hip_atomic_fetch_add(&flags[xt], 1, __ATOMIC_RELEASE, __HIP_MEMORY_SCOPE_AGENT);
        return;
    }

    // ================= scan block (R13-verbatim) =================
    if (threadIdx.x >= 128) return;   // waves 2..7 unused (exit before any barrier)
    const float DT = 0.001f;
    float* ring = (float*)ldsraw;                  // 2*CH*HH floats = 16 KB
    float* wc   = ring + 2 * CH * HH;              // CROWS*HH floats = 128 KB
    int b = gx;
    int lane = threadIdx.x & 63;
    int wid = threadIdx.x >> 6;

    // cooperative wcache fill: w_recP rows 0..127 (128 threads, 64 iters)
    {
        const float4* src = (const float4*)w_recP;
        float4* dst = (float4*)wc;
#pragma unroll
        for (int q = 0; q < (CROWS * HH / 4) / 128; ++q)
            dst[q * 128 + threadIdx.x] = src[q * 128 + threadIdx.x];
    }

    if (wid == 1) {
        // ---- producer: flag-wait then stage xw chunks into LDS ring ----
        // chunk c needs t in [8c,8c+8) -> x-tiles 2c, 2c+1 (each ==2 when done)
#define WAITC(CC) do { int x0 = 2 * (CC);                                            \
            _Pragma("unroll")                                                        \
            for (int k = 0; k < 2; ++k)                                              \
                while (__hip_atomic_load(&flags[x0 + k], __ATOMIC_RELAXED,           \
                                         __HIP_MEMORY_SCOPE_AGENT) != 2)             \
                    __builtin_amdgcn_s_sleep(1);                                     \
            (void)__hip_atomic_load(&flags[x0], __ATOMIC_ACQUIRE,                    \
                                    __HIP_MEMORY_SCOPE_AGENT);                       \
        } while (0)
        WAITC(0);
        float4 rb[CH];
#pragma unroll
        for (int r2 = 0; r2 < CH; ++r2)
            rb[r2] = *(const float4*)(outp + ((size_t)r2 * BB + b) * HH + 4 * lane);
#pragma unroll
        for (int r2 = 0; r2 < CH; ++r2)
            *(float4*)&ring[r2 * HH + 4 * lane] = rb[r2];
        __syncthreads();
        for (int c = 0; c < NCH; ++c) {
            if (c + 1 < NCH) {
                WAITC(c + 1);
                int t0 = (c + 1) * CH;
                int lb = ((c + 1) & 1) * (CH * HH);
                float4 sb[CH];
#pragma unroll
                for (int r2 = 0; r2 < CH; ++r2)
                    sb[r2] = *(const float4*)(outp + ((size_t)(t0 + r2) * BB + b) * HH + 4 * lane);
#pragma unroll
                for (int r2 = 0; r2 < CH; ++r2)
                    *(float4*)&ring[lb + r2 * HH + 4 * lane] = sb[r2];
            }
            __syncthreads();
        }
        return;
    }

    // ---- consumer wave: R9 dynamics + immediate while-loop gather,
    //      packed float4 per spike, ascending m0,m1,m2,m3 sum order ----
    int off = b * HH + lane;
    float am[4], bs[4];
#pragma unroll
    for (int j = 0; j < 4; j++) {
        am[j] = DT * clip01(tau_mem[lane + 64 * j]);
        bs[j] = DT * clip01(tau_syn[lane + 64 * j]);
    }

    float vv[4] = {0.f, 0.f, 0.f, 0.f};
    float ii[4] = {0.f, 0.f, 0.f, 0.f};
    float racc[4] = {0.f, 0.f, 0.f, 0.f};
    float zl[4] = {0.f, 0.f, 0.f, 0.f};
    float cur[4], nxt[4];
    unsigned stoff = (unsigned)off;

#define STEP()                                                                      \
    do {                                                                            \
        bool z[4];                                                                  \
        _Pragma("unroll")                                                           \
        for (int j = 0; j < 4; j++) {                                               \
            float vd = vv[j] + am[j] * (ii[j] - vv[j]);     /* v + DT*tmi*(-v+i) */ \
            float id = ii[j] - bs[j] * ii[j];               /* i - DT*tsi*i    */   \
            z[j] = (vd - 1.0f) > 0.0f;                                              \
            float zf = z[j] ? 1.0f : 0.0f;                                          \
            vv[j] = z[j] ? 0.0f : vd;                                               \
            ii[j] = (id + cur[j]) + racc[j];                /* (i_dec+xw)+rec */    \
            __builtin_nontemporal_store(zf, &outp[stoff + j * 64]);                 \
            zl[j] = zf;                                                             \
        }                                                                           \
        stoff += BH;                                                                \
        unsigned long long m0 = __ballot(z[0]);                                     \
        unsigned long long m1 = __ballot(z[1]);                                     \
        unsigned long long m2 = __ballot(z[2]);                                     \
        unsigned long long m3 = __ballot(z[3]);                                     \
        racc[0] = 0.0f; racc[1] = 0.0f; racc[2] = 0.0f; racc[3] = 0.0f;             \
        if ((m0 | m1 | m2 | m3) != 0ull) {                                          \
            unsigned long long m;                                                   \
            m = m0; while (m) { int bit = __builtin_ctzll(m); m &= m - 1;           \
                float4 e = *(const float4*)(wc + (bit << 8) + 4 * lane);            \
                racc[0] += e.x; racc[1] += e.y; racc[2] += e.z; racc[3] += e.w; }   \
            m = m1; while (m) { int bit = __builtin_ctzll(m); m &= m - 1;           \
                float4 e = *(const float4*)(wc + ((64 + bit) << 8) + 4 * lane);     \
                racc[0] += e.x; racc[1] += e.y; racc[2] += e.z; racc[3] += e.w; }   \
            m = m2; while (m) { int bit = __builtin_ctzll(m); m &= m - 1;           \
                float4 e = *(const float4*)(w_recP + ((size_t)(128 + bit) << 8) + 4 * lane); \
                racc[0] += e.x; racc[1] += e.y; racc[2] += e.z; racc[3] += e.w; }   \
            m = m3; while (m) { int bit = __builtin_ctzll(m); m &= m - 1;           \
                float4 e = *(const float4*)(w_recP + ((size_t)(192 + bit) << 8) + 4 * lane); \
                racc[0] += e.x; racc[1] += e.y; racc[2] += e.z; racc[3] += e.w; }   \
        }                                                                           \
    } while (0)

    __syncthreads();   // wcache + chunk 0 staged

    for (int c = 0; c < NCH; ++c) {
        int lb = (c & 1) * (CH * HH);
#pragma unroll
        for (int j = 0; j < 4; j++)
            cur[j] = ring[lb + lane + 64 * j];
        for (int u = 0; u < CH - 1; ++u) {
#pragma unroll
            for (int j = 0; j < 4; j++)
                nxt[j] = ring[lb + (u + 1) * HH + lane + 64 * j];
            STEP();
#pragma unroll
            for (int j = 0; j < 4; j++)
                cur[j] = nxt[j];
        }
        STEP();        // u = CH-1
        __syncthreads();
    }

    // final state: z_f, v_f, i_f (from registers)
#pragma unroll
    for (int j = 0; j < 4; j++) {
        outp[(size_t)TT * BH + b * HH + lane + 64 * j] = zl[j];
        outp[(size_t)TT * BH + BH + b * HH + lane + 64 * j] = vv[j];
        outp[(size_t)TT * BH + 2 * BH + b * HH + lane + 64 * j] = ii[j];
    }
}

extern "C" void kernel_launch(void* const* d_in, const int* in_sizes, int n_in,
                              void* d_out, int out_size, void* d_ws, size_t ws_size,
                              hipStream_t stream) {
    const float* x       = (const float*)d_in[0];
    const float* w_in    = (const float*)d_in[1];
    const float* w_rec   = (const float*)d_in[2];
    const float* tau_syn = (const float*)d_in[3];
    const float* tau_mem = (const float*)d_in[4];
    float* out = (float*)d_out;

    float* w_inT  = (float*)d_ws;              // 65536 floats
    float* w_recP = w_inT + HH * HH;           // 65536 floats
    int*   flags  = (int*)(w_recP + HH * HH);  // NXT ints

    hipMemsetAsync(flags, 0, NXT * sizeof(int), stream);
    transpose2<<<256, 256, 0, stream>>>(w_in, w_rec, w_inT, w_recP);
    fused<<<SCANB + 2 * NXT, 512, 0, stream>>>(x, tau_syn, tau_mem, w_inT, w_recP,
                                               flags, out);
}